// Round 7
// baseline (115.722 us; speedup 1.0000x reference)
//
#include <hip/hip_runtime.h>

#define CC 8
#define KK 64
#define BB 8192
#define NCHUNK 16
#define ROWS_PER_CHUNK (BB / NCHUNK)   // 512

// ---------------- workspace layout (bytes) ----------------
#define OFF_G       0                         // double G[9][K][K] (class 8 = total) = 294912
#define OFF_GSUM    294912                    // float  gsum[C][K]      =   2048
#define OFF_GCOUNT  296960                    // int    gcount[C]       =     32
#define OFF_GFIRST  296992                    // int    gfirst[C]       =     32  (init 0x7f)
#define OFF_INV     297024                    // double invS2[K][K]     =  32768
#define OFF_LOG     329792                    // double logdets[9]      =     72
#define OFF_GPART   329864                    // float Gpart[16][8][4096] = 2097152

__device__ __forceinline__ double readlane_f64(double v, int lane) {
  union { double d; int i[2]; } u, r;
  u.d = v;
  r.i[0] = __builtin_amdgcn_readlane(u.i[0], lane);
  r.i[1] = __builtin_amdgcn_readlane(u.i[1], lane);
  return r.d;
}

// ---------------- pass 1: per-(chunk,class) partial Grams + fused stats ----------------
__global__ __launch_bounds__(256) void gram_stats_kernel(
    const float* __restrict__ mu, const int* __restrict__ labels,
    float* __restrict__ Gpart, float* __restrict__ gsum,
    int* __restrict__ gcount, int* __restrict__ gfirst) {
  int c = blockIdx.y;
  int chunk = blockIdx.x;
  int tid = threadIdx.x;
  int lane = tid & 63, w = tid >> 6;
  int tx = tid & 15, ty = tid >> 4;
  __shared__ float rows[64][KK];
  __shared__ int labs[64];
  __shared__ float ssum[KK];
  double acc[4][4] = {{0.0}};
  float rsum = 0.f;
  int cnt = 0, first = BB;
  int base = chunk * ROWS_PER_CHUNK;
  const float4* mu4 = (const float4*)mu + (size_t)base * (KK / 4);

  if (tid < KK) ssum[tid] = 0.f;

  float4 pf[4];
  int plab = 0;
#pragma unroll
  for (int i = 0; i < 4; ++i) pf[i] = mu4[tid + i * 256];
  if (tid < 64) plab = labels[base + tid];

#pragma unroll 1
  for (int g = 0; g < ROWS_PER_CHUNK / 64; ++g) {
    __syncthreads();
    float4* rows4 = (float4*)&rows[0][0];
#pragma unroll
    for (int i = 0; i < 4; ++i) rows4[tid + i * 256] = pf[i];
    if (tid < 64) labs[tid] = plab;
    __syncthreads();
    if (g + 1 < ROWS_PER_CHUNK / 64) {
#pragma unroll
      for (int i = 0; i < 4; ++i) pf[i] = mu4[(g + 1) * 1024 + tid + i * 256];
      if (tid < 64) plab = labels[base + (g + 1) * 64 + tid];
    }
#pragma unroll 4
    for (int r = 0; r < 16; ++r) {
      int rr = w * 16 + r;
      if (labs[rr] == c) rsum += rows[rr][lane];
    }
    if (lane < 16 && labs[w * 16 + lane] == c) {
      cnt++;
      first = min(first, base + g * 64 + w * 16 + lane);
    }
    unsigned long long m = __ballot(labs[lane] == c);
    while (m) {
      int r = __builtin_ctzll(m);
      m &= m - 1;
      const float4* rw4 = (const float4*)rows[r];
      float4 a4 = rw4[ty], b4 = rw4[tx];
      const float* ai = (const float*)&a4;
      const float* bj = (const float*)&b4;
#pragma unroll
      for (int a = 0; a < 4; ++a)
#pragma unroll
        for (int b = 0; b < 4; ++b) acc[a][b] += (double)ai[a] * (double)bj[b];
    }
  }
  float* Gp = Gpart + ((size_t)chunk * CC + c) * KK * KK;
#pragma unroll
  for (int a = 0; a < 4; ++a)
#pragma unroll
    for (int b = 0; b < 4; ++b)
      Gp[(ty * 4 + a) * KK + tx * 4 + b] = (float)acc[a][b];
  atomicAdd(&ssum[lane], rsum);
  __syncthreads();
  if (tid < KK) {
    float v = ssum[tid];
    if (v != 0.f) atomicAdd(&gsum[c * KK + tid], v);
  }
  if (lane < 16) {
#pragma unroll
    for (int off = 8; off; off >>= 1) {
      cnt += __shfl_down(cnt, off);
      first = min(first, __shfl_down(first, off));
    }
    if (lane == 0 && cnt) {
      atomicAdd(&gcount[c], cnt);
      atomicMin(&gfirst[c], first);
    }
  }
}

// ---------------- pass 1b: reduce partials -> G (f64); class 8 = total ----------------
__global__ __launch_bounds__(256) void greduce_kernel(
    const float* __restrict__ Gpart, double* __restrict__ G) {
  int c = blockIdx.y;                        // 0..8
  int e = blockIdx.x * 256 + threadIdx.x;    // 0..4095
  double s = 0.0;
  if (c < CC) {
#pragma unroll
    for (int p = 0; p < NCHUNK; ++p)
      s += (double)Gpart[((size_t)p * CC + c) * KK * KK + e];
  } else {
#pragma unroll 4
    for (int p = 0; p < NCHUNK; ++p)
#pragma unroll
      for (int c2 = 0; c2 < CC; ++c2)
        s += (double)Gpart[((size_t)p * CC + c2) * KK * KK + e];
  }
  G[(size_t)c * KK * KK + e] = s;
}

// ---------------- pass 2: 4-wave blocked Cholesky, ROLLED loops (I-cache resident) -------
// 9 blocks x 256 threads. Lane = row. Panel factorization redundant per wave (registers +
// readlane via SGPR lane index). Build & trailing split across waves. Block 8 additionally
// computes X = L^{-1} (wave 0) and invS2 = X^T X (4 waves).
__global__ __launch_bounds__(256) void factor_kernel(
    const double* __restrict__ G, const float* __restrict__ cov,
    const float* __restrict__ gsum, const int* __restrict__ gcount,
    double* __restrict__ logdets, double* __restrict__ invS2,
    float* __restrict__ out) {
  int blk = blockIdx.x;
  int tid = threadIdx.x;
  int t = tid & 63;     // row
  int w = tid >> 6;     // wave 0..3
  __shared__ double bufA[KK][KK + 1];
  __shared__ double bufB[KK][KK + 1];
  __shared__ double panelb[8][KK];
  __shared__ double Lb[KK][KK + 1];   // normalized L (block 8 only)
  __shared__ double Ldi[KK];          // 1/L[i][i]   (block 8 only)
  __shared__ double mb[KK];

  bool isS2 = (blk == CC);
  if (isS2 && tid == 0) out[0] = 0.f;   // zero output accumulator for combine

  // ---- mean (redundant per wave; wave 0 publishes) ----
  double safe, ncd, mt;
  if (!isS2) {
    int nc = gcount[blk];
    ncd = (double)nc;
    safe = nc > 0 ? ncd : 1.0;
    mt = (double)gsum[blk * KK + t] / safe;
  } else {
    ncd = (double)BB;
    safe = (double)BB;
    double s = 0.0;
#pragma unroll
    for (int c = 0; c < CC; ++c) s += (double)gsum[c * KK + t];
    mt = s / safe;
  }
  if (w == 0) mb[t] = mt;
  __syncthreads();

  // ---- build Sigma: wave w fills columns [16w, 16w+16) ----
  {
    const double* Gc = G + (size_t)blk * KK * KK;
    double inv_safe = 1.0 / safe;
#pragma unroll 2
    for (int jj = 0; jj < 16; ++jj) {
      int j = w * 16 + jj;
      bufA[t][j] = (double)cov[j * KK + t] + (Gc[j * KK + t] - ncd * mt * mb[j]) * inv_safe;
    }
  }
  __syncthreads();

  // ---- blocked Cholesky: rolled panel loop ----
  double (*cur)[KK + 1] = bufA;
  double (*nxt)[KK + 1] = bufB;
  double ldacc = 0.0;
  int bound = t | 7;
#pragma unroll 1
  for (int p = 0; p < 8; ++p) {
    const int P0 = p * 8;
    double cc_[8];
#pragma unroll
    for (int m = 0; m < 8; ++m) cc_[m] = cur[t][P0 + m];
    double uu[8];
    double pd = 1.0;
#pragma unroll
    for (int m = 0; m < 8; ++m) {
      double akk = readlane_f64(cc_[m], P0 + m);   // uniform SGPR lane -> v_readlane
      pd *= akk;
      double inv;
      asm("v_rcp_f64 %0, %1" : "=v"(inv) : "v"(akk));
      inv = inv * fma(-akk, inv, 2.0);             // 1 Newton step: rel err ~4e-9
      uu[m] = cc_[m] * inv;
      if (w == 0) {
        panelb[m][t] = cc_[m];
        if (isS2) {
          double rsv = sqrt(akk) * inv;            // 1/sqrt(akk)
          Lb[t][P0 + m] = cc_[m] * rsv;
          if (t == 0) Ldi[P0 + m] = rsv;
        }
      }
#pragma unroll
      for (int mm = m + 1; mm < 8; ++mm)
        cc_[mm] -= uu[m] * readlane_f64(cc_[m], P0 + mm);
    }
    ldacc += log(pd);
    __syncthreads();                    // panelb visible
#pragma unroll 1
    for (int jb = p + 1 + w; jb < 8; jb += 4) {    // wave-split trailing update
      int j = jb * 8;
      if (j <= bound) {
        double aj[8];
#pragma unroll
        for (int q = 0; q < 8; ++q) aj[q] = cur[t][j + q];
#pragma unroll
        for (int m = 0; m < 8; ++m)
#pragma unroll
          for (int q = 0; q < 8; ++q)
            aj[q] -= uu[m] * panelb[m][j + q];     // broadcast reads
#pragma unroll
        for (int q = 0; q < 8; ++q) nxt[t][j + q] = aj[q];
      }
    }
    __syncthreads();                    // nxt complete
    { auto tmp = cur; cur = nxt; nxt = tmp; }
  }
  if (tid == 0) logdets[blk] = ldacc;

  // ---- block 8: X = L^{-1} (wave 0, rolled), then invS2 = X^T X (4 waves, rolled) ----
  if (isS2) {
    double (*Xs)[KK] = (double (*)[KK])(&bufA[0][0]);   // reuse bufA (8 swaps -> cur==bufA)
    if (w == 0) {
#pragma unroll 1
      for (int g = 0; g < 8; ++g) {
        int I0 = g * 8;
        double sv[8];
#pragma unroll
        for (int m = 0; m < 8; ++m) sv[m] = 0.0;
#pragma unroll 2
        for (int j = 0; j < I0; ++j) {
          double xj = Xs[j][t];                   // own column, lane-consecutive
#pragma unroll
          for (int m = 0; m < 8; ++m) sv[m] += Lb[I0 + m][j] * xj;  // broadcast
        }
#pragma unroll
        for (int m = 0; m < 8; ++m) {
          int i = I0 + m;
          double x = (((i == t) ? 1.0 : 0.0) - sv[m]) * Ldi[i];
#pragma unroll
          for (int mm = m + 1; mm < 8; ++mm) sv[mm] += Lb[I0 + mm][i] * x;
          Xs[i][t] = x;                           // zeros for i<t fall out naturally
        }
      }
    }
    __syncthreads();
    // invS2[r][c] = sum_{k>=max(r,c)} X[k][r] X[k][c]; rows round-robin across waves
#pragma unroll 1
    for (int rr = 0; rr < 16; ++rr) {
      int r = w + rr * 4;
      int k0 = r > t ? r : t;          // X strictly-lower both ways
      double s = 0.0;
#pragma unroll 2
      for (int k = k0; k < KK; ++k) s += Xs[k][r] * Xs[k][t];
      invS2[r * KK + t] = s;           // coalesced
    }
  }
}

// ---------------- pass 3: per-class KL + weighted atomic combine ----------------
__global__ __launch_bounds__(64) void combine_kernel(
    const double* __restrict__ G, const double* __restrict__ invS2,
    const double* __restrict__ logdets, const float* __restrict__ cov,
    const int* __restrict__ gcount, const int* __restrict__ gfirst,
    const float* __restrict__ gsum, float* __restrict__ out) {
  int c = blockIdx.x;
  int t = threadIdx.x;
  __shared__ double mv[KK];
  __shared__ double dv[KK];

  double mtot;
  {
    double s = 0.0;
#pragma unroll
    for (int cc2 = 0; cc2 < CC; ++cc2) s += (double)gsum[cc2 * KK + t];
    mtot = s / (double)BB;
  }
  int nc = gcount[c];
  double safe = nc > 0 ? (double)nc : 1.0;
  double mt = (double)gsum[c * KK + t] / safe;
  double dt = mtot - mt;
  mv[t] = mt;
  dv[t] = dt;

  const double* Gc = G + (size_t)c * KK * KK;
  double tg = 0.0, qm = 0.0, qd = 0.0, tic = 0.0;
#pragma unroll 4
  for (int m = 0; m < KK; ++m) {
    double w = invS2[m * KK + t];
    tic += w * (double)cov[m * KK + t];
    tg += w * Gc[m * KK + t];
    qm += w * mv[m];
    qd += w * dv[m];
  }
  qm *= mt;
  qd *= dt;
#pragma unroll
  for (int m = 32; m; m >>= 1) {
    tg += __shfl_down(tg, m);
    qm += __shfl_down(qm, m);
    qd += __shfl_down(qd, m);
    tic += __shfl_down(tic, m);
  }
  if (t == 0) {
    int best = 0;
    long long bv = -2;
    for (int cc2 = 0; cc2 < CC; ++cc2) {
      long long v = gcount[cc2] > 0 ? (long long)gfirst[cc2] : -1;
      if (v > bv) { bv = v; best = cc2; }
    }
    double tr = tic + (tg - (double)nc * qm) / safe;
    double kl = 0.5 * (tr + qd - (double)KK + logdets[CC] - logdets[c]);
    double wgt = (nc > 0 && c != best) ? (double)nc : 0.0;
    atomicAdd(out, (float)(kl * wgt / (double)BB));
  }
}

extern "C" void kernel_launch(void* const* d_in, const int* in_sizes, int n_in,
                              void* d_out, int out_size, void* d_ws, size_t ws_size,
                              hipStream_t stream) {
  (void)in_sizes; (void)n_in; (void)out_size; (void)ws_size;
  const float* mu = (const float*)d_in[0];
  const int* labels = (const int*)d_in[1];
  const float* cov = (const float*)d_in[2];
  float* out = (float*)d_out;
  char* ws = (char*)d_ws;

  double* G = (double*)(ws + OFF_G);
  float* gsum = (float*)(ws + OFF_GSUM);
  int* gcount = (int*)(ws + OFF_GCOUNT);
  int* gfirst = (int*)(ws + OFF_GFIRST);
  double* invS2 = (double*)(ws + OFF_INV);
  double* logdets = (double*)(ws + OFF_LOG);
  float* Gpart = (float*)(ws + OFF_GPART);

  // zero gsum+gcount; gfirst -> 0x7f7f7f7f (+inf for atomicMin). G/Gpart fully overwritten.
  hipMemsetAsync(ws + OFF_GSUM, 0, OFF_GFIRST - OFF_GSUM, stream);
  hipMemsetAsync(ws + OFF_GFIRST, 0x7f, CC * sizeof(int), stream);

  gram_stats_kernel<<<dim3(NCHUNK, CC), 256, 0, stream>>>(mu, labels, Gpart, gsum, gcount, gfirst);
  greduce_kernel<<<dim3(16, CC + 1), 256, 0, stream>>>(Gpart, G);
  factor_kernel<<<CC + 1, 256, 0, stream>>>(G, cov, gsum, gcount, logdets, invS2, out);
  combine_kernel<<<CC, 64, 0, stream>>>(G, invS2, logdets, cov, gcount, gfirst, gsum, out);
}